// Round 2
// baseline (661.602 us; speedup 1.0000x reference)
//
#include <hip/hip_runtime.h>
#include <hip/hip_bf16.h>
#include <cstdint>

#define N_HEAD 16
#define HEAD_DIM 128

typedef __bf16 bf16;
typedef __bf16 bf16x8 __attribute__((ext_vector_type(8)));
typedef __bf16 bf16x4 __attribute__((ext_vector_type(4)));
typedef float f32x4 __attribute__((ext_vector_type(4)));

// async global->LDS 16B (per-lane lds addr must be base + lane*16)
__device__ __forceinline__ void gload_lds16(const void* g, void* l) {
  auto gp = reinterpret_cast<const __attribute__((address_space(1))) char*>(
      reinterpret_cast<uintptr_t>(g));
  auto lp = reinterpret_cast<__attribute__((address_space(3))) char*>(
      reinterpret_cast<uintptr_t>(l));
  __builtin_amdgcn_global_load_lds(gp, lp, 16, 0, 0);
}

// ---------------- fp32 -> bf16 convert (vectorized) ----------------
__global__ __launch_bounds__(256) void cvt_bf16(const float* __restrict__ in,
                                                bf16* __restrict__ out, int n4) {
  int i = blockIdx.x * 256 + threadIdx.x;
  if (i >= n4) return;
  const float4 f = reinterpret_cast<const float4*>(in)[i];
  bf16x4 o;
  o.x = (bf16)f.x; o.y = (bf16)f.y; o.z = (bf16)f.z; o.w = (bf16)f.w;
  reinterpret_cast<bf16x4*>(out)[i] = o;
}

// ---------------- GEMM: C[M,N] = A[M,K] * B[N,K]^T (both row-major, bf16) ----
// 128x128 tile, BK=32, 4 waves (2x2 of 64x64), 16x16x32 bf16 MFMA.
template <typename OutT>
__global__ __launch_bounds__(256) void gemm_bt(
    const bf16* __restrict__ A, const bf16* __restrict__ Bt,
    OutT* __restrict__ C, int M, int N, int K) {
  __shared__ __align__(16) bf16 As[128 * 32];
  __shared__ __align__(16) bf16 Bs[128 * 32];
  const int tid = threadIdx.x;
  const int lane = tid & 63;
  const int wave = tid >> 6;
  const int wm = (wave >> 1) * 64;
  const int wn = (wave & 1) * 64;
  const int lr = lane & 15;
  const int lk = (lane >> 4) * 8;

  const bf16* Ab = A + (size_t)blockIdx.y * 128 * K;
  const bf16* Bb = Bt + (size_t)blockIdx.x * 128 * K;

  const int r0 = tid >> 2;        // 0..63, +64 on second pass
  const int c0 = (tid & 3) * 8;   // k-offset in elements

  f32x4 acc[4][4] = {};

  for (int k0 = 0; k0 < K; k0 += 32) {
    __syncthreads();
    gload_lds16(Ab + (size_t)r0 * K + k0 + c0, As + (size_t)tid * 8);
    gload_lds16(Ab + (size_t)(r0 + 64) * K + k0 + c0, As + (size_t)(256 + tid) * 8);
    gload_lds16(Bb + (size_t)r0 * K + k0 + c0, Bs + (size_t)tid * 8);
    gload_lds16(Bb + (size_t)(r0 + 64) * K + k0 + c0, Bs + (size_t)(256 + tid) * 8);
    __syncthreads();

    bf16x8 a[4], b[4];
#pragma unroll
    for (int i = 0; i < 4; ++i)
      a[i] = *reinterpret_cast<const bf16x8*>(As + (wm + i * 16 + lr) * 32 + lk);
#pragma unroll
    for (int j = 0; j < 4; ++j)
      b[j] = *reinterpret_cast<const bf16x8*>(Bs + (wn + j * 16 + lr) * 32 + lk);
#pragma unroll
    for (int i = 0; i < 4; ++i)
#pragma unroll
      for (int j = 0; j < 4; ++j)
        acc[i][j] = __builtin_amdgcn_mfma_f32_16x16x32_bf16(a[i], b[j], acc[i][j], 0, 0, 0);
  }

  const int orow = blockIdx.y * 128 + wm + (lane >> 4) * 4;
  const int ocol = blockIdx.x * 128 + wn + lr;
#pragma unroll
  for (int i = 0; i < 4; ++i)
#pragma unroll
    for (int j = 0; j < 4; ++j)
#pragma unroll
      for (int r = 0; r < 4; ++r)
        C[(size_t)(orow + i * 16 + r) * N + (ocol + j * 16)] = (OutT)acc[i][j][r];
}

// ---------------- rope + rms-norm, in-place on q and k (bf16) ---------------
// grid: (B*T, H/4, 2[q|k]); one wave per head; lane i handles pair (i, i+64)
// q gets 1.2 * 1/sqrt(128) * log2(e) folded in (attn softmax runs in exp2 domain)
__global__ __launch_bounds__(256) void rope_rms(
    bf16* __restrict__ q, bf16* __restrict__ k,
    const float* __restrict__ cs, const float* __restrict__ sn, int T) {
  const int bt = blockIdx.x;
  const int t = bt % T;
  const int wave = threadIdx.x >> 6;
  const int lane = threadIdx.x & 63;
  const int h = blockIdx.y * 4 + wave;
  bf16* p = (blockIdx.z ? k : q) + (size_t)bt * (N_HEAD * HEAD_DIM) + h * HEAD_DIM;
  // q: 1.2 * 0.08838834764831845 * 1.4426950408889634
  const float oscale = blockIdx.z ? 1.2f : 0.15302091809294977f;
  const float c = cs[t * 64 + lane];
  const float s = sn[t * 64 + lane];
  const float x1 = (float)p[lane];
  const float x2 = (float)p[lane + 64];
  const float r1 = x1 * c + x2 * s;
  const float r2 = x2 * c - x1 * s;
  float ss = r1 * r1 + r2 * r2;
#pragma unroll
  for (int m = 1; m < 64; m <<= 1) ss += __shfl_xor(ss, m);
  const float sc = oscale * rsqrtf(ss * (1.0f / 128.0f) + 1e-6f);
  p[lane] = (bf16)(r1 * sc);
  p[lane + 64] = (bf16)(r2 * sc);
}

// ---------------- gate + transpose: vT[b][h][d][t] = v[b][t][h][d] + gate*ve --
// grid: (T/64, C/64, B), block 256. 64x64 tiles via padded LDS.
__global__ __launch_bounds__(256) void gate_transpose(
    const bf16* __restrict__ v, const float* __restrict__ x,
    const float* __restrict__ ve, const float* __restrict__ Wg,
    bf16* __restrict__ vT, int T) {
  const int C = N_HEAD * HEAD_DIM;
  const int t0 = blockIdx.x * 64;
  const int c0 = blockIdx.y * 64;
  const int b = blockIdx.z;
  const int h = c0 >> 7;

  __shared__ float gs[64];
  __shared__ __align__(16) bf16 tile[64][72];

  if (threadIdx.x < 64) {
    const float* xr = x + (size_t)(b * T + t0 + threadIdx.x) * C;
    float a = 0.f;
#pragma unroll
    for (int j = 0; j < 12; ++j) a += xr[j] * Wg[h * 12 + j];
    gs[threadIdx.x] = 3.f / (1.f + __expf(-a));
  }
  __syncthreads();

  {
    const int r = threadIdx.x >> 2;
    const int cc = (threadIdx.x & 3) * 16;
    const size_t row = (size_t)(b * T + t0 + r) * C + c0 + cc;
    bf16x8 a0 = *reinterpret_cast<const bf16x8*>(v + row);
    bf16x8 a1 = *reinterpret_cast<const bf16x8*>(v + row + 8);
    const float g = gs[r];
    bf16x8 o0, o1;
#pragma unroll
    for (int i = 0; i < 8; ++i) o0[i] = (bf16)((float)a0[i] + g * ve[row + i]);
#pragma unroll
    for (int i = 0; i < 8; ++i) o1[i] = (bf16)((float)a1[i] + g * ve[row + 8 + i]);
    *reinterpret_cast<bf16x8*>(&tile[r][cc]) = o0;
    *reinterpret_cast<bf16x8*>(&tile[r][cc + 8]) = o1;
  }
  __syncthreads();
  {
    const int dr = threadIdx.x >> 2;        // col of tile = d offset
    const int tc = (threadIdx.x & 3) * 16;  // row of tile = t offset
    bf16x8 o0, o1;
#pragma unroll
    for (int i = 0; i < 8; ++i) o0[i] = tile[tc + i][dr];
#pragma unroll
    for (int i = 0; i < 8; ++i) o1[i] = tile[tc + 8 + i][dr];
    const size_t orow =
        ((size_t)((b * N_HEAD + h) * HEAD_DIM) + (c0 & 127) + dr) * T + t0 + tc;
    *reinterpret_cast<bf16x8*>(vT + orow) = o0;
    *reinterpret_cast<bf16x8*>(vT + orow + 8) = o1;
  }
}

// ---------------- flash attention, sliding window, barrier-free ------------
// grid: (T/64, H, B); 4 waves x 16 q-rows each; keys in chunks of 64.
// S^T = K*Q^T so softmax state is per-lane scalar (q = lane&15).
// O^T accumulated; V^T read directly from pre-transposed global vT.
__global__ __launch_bounds__(256, 4) void attn(
    const bf16* __restrict__ q, const bf16* __restrict__ k,
    const bf16* __restrict__ vT, bf16* __restrict__ y,
    const int* __restrict__ wptr, int T) {
  const int C = N_HEAD * HEAD_DIM;
  const int qb = blockIdx.x * 64;
  const int h = blockIdx.y;
  const int b = blockIdx.z;
  const int wave = threadIdx.x >> 6;
  const int lane = threadIdx.x & 63;
  const int lm = lane & 15;
  const int quad = lane >> 4;

  const int w = wptr[0];
  const int W = (w > 0 && w < T) ? w : (1 << 30);

  // per-wave P buffer: C-layout -> Bt-layout round trip (wave-synchronous,
  // no __syncthreads: each wave touches only its own slice; DS ops in-order)
  __shared__ __align__(16) bf16 Pb[4][16][72];

  const size_t bh = (size_t)b * T * C + (size_t)h * HEAD_DIM;
  const bf16* kb = k + bh;
  const bf16* vb = vT + (size_t)((b * N_HEAD + h) * HEAD_DIM) * T;  // [128][T]

  const int qg0 = qb + wave * 16;
  const bf16* qrow = q + bh + (size_t)(qg0 + lm) * C;
  bf16x8 qf[4];
#pragma unroll
  for (int c = 0; c < 4; ++c)
    qf[c] = *reinterpret_cast<const bf16x8*>(qrow + c * 32 + quad * 8);

  float mrun = -1e30f, lrun = 0.f;
  f32x4 oacc[8] = {};

  int kstart = qb - W;
  if (kstart < 0) kstart = 0;
  kstart &= ~63;
  const int qr = qg0 + lm;  // this lane's q row (softmax owner)

  for (int kc = kstart; kc <= qb + 63; kc += 64) {
    // S^T[key][q] for 64 keys x 16 q
    f32x4 st[4] = {};
#pragma unroll
    for (int g = 0; g < 4; ++g) {
      const bf16* kr = kb + (size_t)(kc + g * 16 + lm) * C;
#pragma unroll
      for (int c = 0; c < 4; ++c) {
        bf16x8 kf = *reinterpret_cast<const bf16x8*>(kr + c * 32 + quad * 8);
        st[g] = __builtin_amdgcn_mfma_f32_16x16x32_bf16(kf, qf[c], st[g], 0, 0, 0);
      }
    }
    // mask + local max (lane owns keys g*16+quad*4+r, single q row qr)
    float mx = -1e30f;
#pragma unroll
    for (int g = 0; g < 4; ++g)
#pragma unroll
      for (int r = 0; r < 4; ++r) {
        const int key = kc + g * 16 + quad * 4 + r;
        const bool valid = (key <= qr) && (qr - key <= W);
        st[g][r] = valid ? st[g][r] : -1e30f;
        mx = fmaxf(mx, st[g][r]);
      }
    mx = fmaxf(mx, __shfl_xor(mx, 16));
    mx = fmaxf(mx, __shfl_xor(mx, 32));
    const float mnew = fmaxf(mrun, mx);
    const float alpha = __builtin_amdgcn_exp2f(mrun - mnew);
    mrun = mnew;
    // p = exp2(s - mnew); masked -> exp2(-huge) = 0. If the whole prefix was
    // masked (mnew still -1e30) garbage accumulates but alpha=exp2(-huge)=0
    // wipes it at the first real key. Every q row sees >=1 real key overall.
    float rs = 0.f;
#pragma unroll
    for (int g = 0; g < 4; ++g) {
      bf16x4 pk;
#pragma unroll
      for (int r = 0; r < 4; ++r) {
        const float p = __builtin_amdgcn_exp2f(st[g][r] - mnew);
        rs += p;
        pk[r] = (bf16)p;
      }
      *reinterpret_cast<bf16x4*>(&Pb[wave][lm][g * 16 + quad * 4]) = pk;
    }
    rs += __shfl_xor(rs, 16);
    rs += __shfl_xor(rs, 32);
    lrun = lrun * alpha + rs;
#pragma unroll
    for (int dc = 0; dc < 8; ++dc)
#pragma unroll
      for (int r = 0; r < 4; ++r) oacc[dc][r] *= alpha;
    // O^T += V^T * P^T : A = vT rows (d), Bt = P rows (q)
#pragma unroll
    for (int c2 = 0; c2 < 2; ++c2) {
      const bf16x8 pf =
          *reinterpret_cast<const bf16x8*>(&Pb[wave][lm][c2 * 32 + quad * 8]);
#pragma unroll
      for (int dc = 0; dc < 8; ++dc) {
        const bf16x8 vf = *reinterpret_cast<const bf16x8*>(
            vb + (size_t)(dc * 16 + lm) * T + kc + c2 * 32 + quad * 8);
        oacc[dc] = __builtin_amdgcn_mfma_f32_16x16x32_bf16(vf, pf, oacc[dc], 0, 0, 0);
      }
    }
  }

  const float inv = 1.f / lrun;
  bf16* yr = y + (size_t)b * T * C + (size_t)(qg0 + lm) * C + h * HEAD_DIM;
#pragma unroll
  for (int dc = 0; dc < 8; ++dc) {
    bf16x4 o;
#pragma unroll
    for (int r = 0; r < 4; ++r) o[r] = (bf16)(oacc[dc][r] * inv);
    *reinterpret_cast<bf16x4*>(yr + dc * 16 + quad * 4) = o;
  }
}

extern "C" void kernel_launch(void* const* d_in, const int* in_sizes, int n_in,
                              void* d_out, int out_size, void* d_ws, size_t ws_size,
                              hipStream_t stream) {
  const float* x  = (const float*)d_in[0];
  const float* ve = (const float*)d_in[1];
  const float* Wq = (const float*)d_in[2];
  const float* Wk = (const float*)d_in[3];
  const float* Wv = (const float*)d_in[4];
  const float* Wp = (const float*)d_in[5];
  const float* Wg = (const float*)d_in[6];
  const float* cs = (const float*)d_in[7];
  const float* sn = (const float*)d_in[8];
  const int*   wl = (const int*)d_in[9];
  float* out = (float*)d_out;

  const int C = N_HEAD * HEAD_DIM;       // 2048
  const int T = in_sizes[7] / (HEAD_DIM / 2);
  const int B = in_sizes[0] / (T * C);
  const int M = B * T;

  bf16* xb   = (bf16*)d_ws;
  bf16* wqb  = xb  + (size_t)M * C;
  bf16* wkb  = wqb + (size_t)C * C;
  bf16* wvb  = wkb + (size_t)C * C;
  bf16* wpb  = wvb + (size_t)C * C;
  bf16* qbuf = wpb + (size_t)C * C;
  bf16* kbuf = qbuf + (size_t)M * C;
  bf16* vbuf = kbuf + (size_t)M * C;
  bf16* ybuf = vbuf + (size_t)M * C;
  bf16* vTb  = xb;  // x's bf16 copy is dead after the QKV GEMMs; reuse for V^T

  const int nx4 = M * C / 4, nw4 = C * C / 4;
  cvt_bf16<<<(nx4 + 255) / 256, 256, 0, stream>>>(x, xb, nx4);
  cvt_bf16<<<(nw4 + 255) / 256, 256, 0, stream>>>(Wq, wqb, nw4);
  cvt_bf16<<<(nw4 + 255) / 256, 256, 0, stream>>>(Wk, wkb, nw4);
  cvt_bf16<<<(nw4 + 255) / 256, 256, 0, stream>>>(Wv, wvb, nw4);
  cvt_bf16<<<(nw4 + 255) / 256, 256, 0, stream>>>(Wp, wpb, nw4);

  dim3 gg(C / 128, M / 128);
  gemm_bt<bf16><<<gg, 256, 0, stream>>>(xb, wqb, qbuf, M, C, C);
  gemm_bt<bf16><<<gg, 256, 0, stream>>>(xb, wkb, kbuf, M, C, C);
  gemm_bt<bf16><<<gg, 256, 0, stream>>>(xb, wvb, vbuf, M, C, C);

  rope_rms<<<dim3(M, N_HEAD / 4, 2), 256, 0, stream>>>(qbuf, kbuf, cs, sn, T);
  gate_transpose<<<dim3(T / 64, C / 64, B), 256, 0, stream>>>(vbuf, x, ve, Wg, vTb, T);
  attn<<<dim3(T / 64, N_HEAD, B), 256, 0, stream>>>(qbuf, kbuf, vTb, ybuf, wl, T);

  gemm_bt<float><<<gg, 256, 0, stream>>>(ybuf, wpb, out, M, C, C);
}

// Round 3
// 472.067 us; speedup vs baseline: 1.4015x; 1.4015x over previous
//
#include <hip/hip_runtime.h>
#include <hip/hip_bf16.h>
#include <cstdint>

#define N_HEAD 16
#define HEAD_DIM 128

typedef __bf16 bf16;
typedef __bf16 bf16x8 __attribute__((ext_vector_type(8)));
typedef __bf16 bf16x4 __attribute__((ext_vector_type(4)));
typedef float f32x4 __attribute__((ext_vector_type(4)));

// async global->LDS 16B (per-lane lds addr must be base + lane*16)
__device__ __forceinline__ void gload_lds16(const void* g, void* l) {
  auto gp = reinterpret_cast<const __attribute__((address_space(1))) char*>(
      reinterpret_cast<uintptr_t>(g));
  auto lp = reinterpret_cast<__attribute__((address_space(3))) char*>(
      reinterpret_cast<uintptr_t>(l));
  __builtin_amdgcn_global_load_lds(gp, lp, 16, 0, 0);
}

// ---------------- fp32 -> bf16 convert (vectorized) ----------------
__global__ __launch_bounds__(256) void cvt_bf16(const float* __restrict__ in,
                                                bf16* __restrict__ out, int n4) {
  int i = blockIdx.x * 256 + threadIdx.x;
  if (i >= n4) return;
  const float4 f = reinterpret_cast<const float4*>(in)[i];
  bf16x4 o;
  o.x = (bf16)f.x; o.y = (bf16)f.y; o.z = (bf16)f.z; o.w = (bf16)f.w;
  reinterpret_cast<bf16x4*>(out)[i] = o;
}

// ---------------- GEMM: C[M,N] = A[M,K] * B[N,K]^T (both row-major, bf16) ----
// 128x128 tile, BK=32, 4 waves (2x2 of 64x64), 16x16x32 bf16 MFMA.
template <typename OutT>
__global__ __launch_bounds__(256) void gemm_bt(
    const bf16* __restrict__ A, const bf16* __restrict__ Bt,
    OutT* __restrict__ C, int M, int N, int K) {
  __shared__ __align__(16) bf16 As[128 * 32];
  __shared__ __align__(16) bf16 Bs[128 * 32];
  const int tid = threadIdx.x;
  const int lane = tid & 63;
  const int wave = tid >> 6;
  const int wm = (wave >> 1) * 64;
  const int wn = (wave & 1) * 64;
  const int lr = lane & 15;
  const int lk = (lane >> 4) * 8;

  const bf16* Ab = A + (size_t)blockIdx.y * 128 * K;
  const bf16* Bb = Bt + (size_t)blockIdx.x * 128 * K;

  const int r0 = tid >> 2;        // 0..63, +64 on second pass
  const int c0 = (tid & 3) * 8;   // k-offset in elements

  f32x4 acc[4][4] = {};

  for (int k0 = 0; k0 < K; k0 += 32) {
    __syncthreads();
    gload_lds16(Ab + (size_t)r0 * K + k0 + c0, As + (size_t)tid * 8);
    gload_lds16(Ab + (size_t)(r0 + 64) * K + k0 + c0, As + (size_t)(256 + tid) * 8);
    gload_lds16(Bb + (size_t)r0 * K + k0 + c0, Bs + (size_t)tid * 8);
    gload_lds16(Bb + (size_t)(r0 + 64) * K + k0 + c0, Bs + (size_t)(256 + tid) * 8);
    __syncthreads();

    bf16x8 a[4], b[4];
#pragma unroll
    for (int i = 0; i < 4; ++i)
      a[i] = *reinterpret_cast<const bf16x8*>(As + (wm + i * 16 + lr) * 32 + lk);
#pragma unroll
    for (int j = 0; j < 4; ++j)
      b[j] = *reinterpret_cast<const bf16x8*>(Bs + (wn + j * 16 + lr) * 32 + lk);
#pragma unroll
    for (int i = 0; i < 4; ++i)
#pragma unroll
      for (int j = 0; j < 4; ++j)
        acc[i][j] = __builtin_amdgcn_mfma_f32_16x16x32_bf16(a[i], b[j], acc[i][j], 0, 0, 0);
  }

  const int orow = blockIdx.y * 128 + wm + (lane >> 4) * 4;
  const int ocol = blockIdx.x * 128 + wn + lr;
#pragma unroll
  for (int i = 0; i < 4; ++i)
#pragma unroll
    for (int j = 0; j < 4; ++j)
#pragma unroll
      for (int r = 0; r < 4; ++r)
        C[(size_t)(orow + i * 16 + r) * N + (ocol + j * 16)] = (OutT)acc[i][j][r];
}

// ---------------- rope + rms-norm, in-place on q,k inside qkv buffer --------
// grid: (B*T, H/4, 2[q|k]); one wave per head; lane i handles pair (i, i+64)
// q gets 1.2 * 1/sqrt(128) * log2(e) folded in (attn softmax runs in exp2 domain)
__global__ __launch_bounds__(256) void rope_rms(
    bf16* __restrict__ qkv, const float* __restrict__ cs,
    const float* __restrict__ sn, int T) {
  const int C = N_HEAD * HEAD_DIM;
  const int S = 3 * C;
  const int bt = blockIdx.x;
  const int t = bt % T;
  const int wave = threadIdx.x >> 6;
  const int lane = threadIdx.x & 63;
  const int h = blockIdx.y * 4 + wave;
  bf16* p = qkv + (size_t)bt * S + (blockIdx.z ? C : 0) + h * HEAD_DIM;
  // q: 1.2 * 0.08838834764831845 * 1.4426950408889634
  const float oscale = blockIdx.z ? 1.2f : 0.15302091809294977f;
  const float c = cs[t * 64 + lane];
  const float s = sn[t * 64 + lane];
  const float x1 = (float)p[lane];
  const float x2 = (float)p[lane + 64];
  const float r1 = x1 * c + x2 * s;
  const float r2 = x2 * c - x1 * s;
  float ss = r1 * r1 + r2 * r2;
#pragma unroll
  for (int m = 1; m < 64; m <<= 1) ss += __shfl_xor(ss, m);
  const float sc = oscale * rsqrtf(ss * (1.0f / 128.0f) + 1e-6f);
  p[lane] = (bf16)(r1 * sc);
  p[lane + 64] = (bf16)(r2 * sc);
}

// ---------------- gate + transpose: vT[b][h][d][t] = v[b][t][h][d] + gate*ve --
// v lives inside qkv at column offset 2C (row stride 3C).
// grid: (T/64, C/64, B), block 256. 64x64 tiles via padded LDS.
__global__ __launch_bounds__(256) void gate_transpose(
    const bf16* __restrict__ qkv, const float* __restrict__ x,
    const float* __restrict__ ve, const float* __restrict__ Wg,
    bf16* __restrict__ vT, int T) {
  const int C = N_HEAD * HEAD_DIM;
  const int S = 3 * C;
  const int t0 = blockIdx.x * 64;
  const int c0 = blockIdx.y * 64;
  const int b = blockIdx.z;
  const int h = c0 >> 7;

  __shared__ float gs[64];
  __shared__ __align__(16) bf16 tile[64][72];

  if (threadIdx.x < 64) {
    const float* xr = x + (size_t)(b * T + t0 + threadIdx.x) * C;
    float a = 0.f;
#pragma unroll
    for (int j = 0; j < 12; ++j) a += xr[j] * Wg[h * 12 + j];
    gs[threadIdx.x] = 3.f / (1.f + __expf(-a));
  }
  __syncthreads();

  {
    const int r = threadIdx.x >> 2;
    const int cc = (threadIdx.x & 3) * 16;
    const size_t vrow = (size_t)(b * T + t0 + r) * S + 2 * C + c0 + cc;
    const size_t erow = (size_t)(b * T + t0 + r) * C + c0 + cc;
    bf16x8 a0 = *reinterpret_cast<const bf16x8*>(qkv + vrow);
    bf16x8 a1 = *reinterpret_cast<const bf16x8*>(qkv + vrow + 8);
    const float g = gs[r];
    bf16x8 o0, o1;
#pragma unroll
    for (int i = 0; i < 8; ++i) o0[i] = (bf16)((float)a0[i] + g * ve[erow + i]);
#pragma unroll
    for (int i = 0; i < 8; ++i) o1[i] = (bf16)((float)a1[i] + g * ve[erow + 8 + i]);
    *reinterpret_cast<bf16x8*>(&tile[r][cc]) = o0;
    *reinterpret_cast<bf16x8*>(&tile[r][cc + 8]) = o1;
  }
  __syncthreads();
  {
    const int dr = threadIdx.x >> 2;        // col of tile = d offset
    const int tc = (threadIdx.x & 3) * 16;  // row of tile = t offset
    bf16x8 o0, o1;
#pragma unroll
    for (int i = 0; i < 8; ++i) o0[i] = tile[tc + i][dr];
#pragma unroll
    for (int i = 0; i < 8; ++i) o1[i] = tile[tc + 8 + i][dr];
    const size_t orow =
        ((size_t)((b * N_HEAD + h) * HEAD_DIM) + (c0 & 127) + dr) * T + t0 + tc;
    *reinterpret_cast<bf16x8*>(vT + orow) = o0;
    *reinterpret_cast<bf16x8*>(vT + orow + 8) = o1;
  }
}

// ---------------- flash attention, sliding window, LDS-staged --------------
// grid: (T/64, H, B); 4 waves x 16 q-rows; 64-key chunks staged in LDS.
// S^T = K*Q^T (per-lane scalar softmax, q = lane&15); O^T accumulated;
// K and V^T tiles cooperatively staged via global_load_lds (m97 sub-tile
// layout [rows][32] so ds_read_b128 fragment reads match the GEMM pattern).
__global__ __launch_bounds__(256, 3) void attn(
    const bf16* __restrict__ qkv, const bf16* __restrict__ vT,
    bf16* __restrict__ y, const int* __restrict__ wptr, int T) {
  const int C = N_HEAD * HEAD_DIM;
  const int S = 3 * C;
  const int qb = blockIdx.x * 64;
  const int h = blockIdx.y;
  const int b = blockIdx.z;
  const int tid = threadIdx.x;
  const int wave = tid >> 6;
  const int lane = tid & 63;
  const int lm = lane & 15;
  const int quad = lane >> 4;

  const int w = wptr[0];
  const int W = (w > 0 && w < T) ? w : (1 << 30);

  __shared__ __align__(16) bf16 Ks[4][64][32];   // [d-chunk][key][32]  16 KB
  __shared__ __align__(16) bf16 Vs[2][128][32];  // [key-chunk][d][32]  16 KB
  __shared__ __align__(16) bf16 Pb[4][16][72];   // per-wave P          9 KB

  const bf16* kb = qkv + (size_t)b * T * S + C + (size_t)h * HEAD_DIM;
  const bf16* vb = vT + (size_t)((b * N_HEAD + h) * HEAD_DIM) * T;  // [128][T]

  const int qg0 = qb + wave * 16;
  const bf16* qrow = qkv + (size_t)(b * T + qg0 + lm) * S + h * HEAD_DIM;
  bf16x8 qf[4];
#pragma unroll
  for (int c = 0; c < 4; ++c)
    qf[c] = *reinterpret_cast<const bf16x8*>(qrow + c * 32 + quad * 8);

  float mrun = -1e30f, lrun = 0.f;
  f32x4 oacc[8] = {};

  int kstart = qb - W;
  if (kstart < 0) kstart = 0;
  kstart &= ~63;
  const int qr = qg0 + lm;  // this lane's q row (softmax owner)

  const int sr = tid >> 2;         // staging row 0..63
  const int sc = (tid & 3) * 8;    // staging col offset (elements)

  for (int kc = kstart; kc <= qb + 63; kc += 64) {
    __syncthreads();
    // stage K tile: 4 sub-tiles [64 keys][32 d]
#pragma unroll
    for (int c = 0; c < 4; ++c)
      gload_lds16(kb + (size_t)(kc + sr) * S + c * 32 + sc, &Ks[c][0][0] + tid * 8);
    // stage V^T tile: 2 sub-tiles [128 d][32 keys]
#pragma unroll
    for (int c2 = 0; c2 < 2; ++c2)
#pragma unroll
      for (int i = 0; i < 2; ++i)
        gload_lds16(vb + (size_t)(i * 64 + sr) * T + kc + c2 * 32 + sc,
                    &Vs[c2][i * 64][0] + tid * 8);
    __syncthreads();

    // S^T[key][q] for 64 keys x 16 q
    f32x4 st[4] = {};
#pragma unroll
    for (int g = 0; g < 4; ++g)
#pragma unroll
      for (int c = 0; c < 4; ++c) {
        const bf16x8 kf =
            *reinterpret_cast<const bf16x8*>(&Ks[c][g * 16 + lm][quad * 8]);
        st[g] = __builtin_amdgcn_mfma_f32_16x16x32_bf16(kf, qf[c], st[g], 0, 0, 0);
      }
    // mask + local max (lane owns keys g*16+quad*4+r, single q row qr)
    float mx = -1e30f;
#pragma unroll
    for (int g = 0; g < 4; ++g)
#pragma unroll
      for (int r = 0; r < 4; ++r) {
        const int key = kc + g * 16 + quad * 4 + r;
        const bool valid = (key <= qr) && (qr - key <= W);
        st[g][r] = valid ? st[g][r] : -1e30f;
        mx = fmaxf(mx, st[g][r]);
      }
    mx = fmaxf(mx, __shfl_xor(mx, 16));
    mx = fmaxf(mx, __shfl_xor(mx, 32));
    const float mnew = fmaxf(mrun, mx);
    const float alpha = __builtin_amdgcn_exp2f(mrun - mnew);
    mrun = mnew;
    float rs = 0.f;
#pragma unroll
    for (int g = 0; g < 4; ++g) {
      bf16x4 pk;
#pragma unroll
      for (int r = 0; r < 4; ++r) {
        const float p = __builtin_amdgcn_exp2f(st[g][r] - mnew);
        rs += p;
        pk[r] = (bf16)p;
      }
      *reinterpret_cast<bf16x4*>(&Pb[wave][lm][g * 16 + quad * 4]) = pk;
    }
    rs += __shfl_xor(rs, 16);
    rs += __shfl_xor(rs, 32);
    lrun = lrun * alpha + rs;
#pragma unroll
    for (int dc = 0; dc < 8; ++dc)
#pragma unroll
      for (int r = 0; r < 4; ++r) oacc[dc][r] *= alpha;
    // O^T += V^T * P^T : A = V^T rows (d) from LDS, Bt = P rows (q) from LDS
#pragma unroll
    for (int c2 = 0; c2 < 2; ++c2) {
      const bf16x8 pf =
          *reinterpret_cast<const bf16x8*>(&Pb[wave][lm][c2 * 32 + quad * 8]);
#pragma unroll
      for (int dc = 0; dc < 8; ++dc) {
        const bf16x8 vf =
            *reinterpret_cast<const bf16x8*>(&Vs[c2][dc * 16 + lm][quad * 8]);
        oacc[dc] = __builtin_amdgcn_mfma_f32_16x16x32_bf16(vf, pf, oacc[dc], 0, 0, 0);
      }
    }
  }

  const float inv = 1.f / lrun;
  bf16* yr = y + (size_t)(b * T + qg0 + lm) * C + h * HEAD_DIM;
#pragma unroll
  for (int dc = 0; dc < 8; ++dc) {
    bf16x4 o;
#pragma unroll
    for (int r = 0; r < 4; ++r) o[r] = (bf16)(oacc[dc][r] * inv);
    *reinterpret_cast<bf16x4*>(yr + dc * 16 + quad * 4) = o;
  }
}

extern "C" void kernel_launch(void* const* d_in, const int* in_sizes, int n_in,
                              void* d_out, int out_size, void* d_ws, size_t ws_size,
                              hipStream_t stream) {
  const float* x  = (const float*)d_in[0];
  const float* ve = (const float*)d_in[1];
  const float* Wq = (const float*)d_in[2];
  const float* Wk = (const float*)d_in[3];
  const float* Wv = (const float*)d_in[4];
  const float* Wp = (const float*)d_in[5];
  const float* Wg = (const float*)d_in[6];
  const float* cs = (const float*)d_in[7];
  const float* sn = (const float*)d_in[8];
  const int*   wl = (const int*)d_in[9];
  float* out = (float*)d_out;

  const int C = N_HEAD * HEAD_DIM;       // 2048
  const int T = in_sizes[7] / (HEAD_DIM / 2);
  const int B = in_sizes[0] / (T * C);
  const int M = B * T;

  bf16* xb   = (bf16*)d_ws;                    // [M][C]
  bf16* wqkv = xb   + (size_t)M * C;           // [3C][C] (Wq|Wk|Wv rows)
  bf16* wpb  = wqkv + (size_t)3 * C * C;       // [C][C]
  bf16* qkv  = wpb  + (size_t)C * C;           // [M][3C]
  bf16* ybuf = qkv  + (size_t)3 * M * C;       // [M][C]
  bf16* vTb  = xb;  // xb dead after QKV GEMM; reuse for V^T [B][H][128][T]

  const int nx4 = M * C / 4, nw4 = C * C / 4;
  cvt_bf16<<<(nx4 + 255) / 256, 256, 0, stream>>>(x, xb, nx4);
  cvt_bf16<<<(nw4 + 255) / 256, 256, 0, stream>>>(Wq, wqkv, nw4);
  cvt_bf16<<<(nw4 + 255) / 256, 256, 0, stream>>>(Wk, wqkv + (size_t)C * C, nw4);
  cvt_bf16<<<(nw4 + 255) / 256, 256, 0, stream>>>(Wv, wqkv + (size_t)2 * C * C, nw4);
  cvt_bf16<<<(nw4 + 255) / 256, 256, 0, stream>>>(Wp, wpb, nw4);

  // fused QKV: [M,3C] = xb[M,K] * wqkv[3C,K]^T
  gemm_bt<bf16><<<dim3(3 * C / 128, M / 128), 256, 0, stream>>>(xb, wqkv, qkv, M, 3 * C, C);

  rope_rms<<<dim3(M, N_HEAD / 4, 2), 256, 0, stream>>>(qkv, cs, sn, T);
  gate_transpose<<<dim3(T / 64, C / 64, B), 256, 0, stream>>>(qkv, x, ve, Wg, vTb, T);
  attn<<<dim3(T / 64, N_HEAD, B), 256, 0, stream>>>(qkv, vTb, ybuf, wl, T);

  gemm_bt<float><<<dim3(C / 128, M / 128), 256, 0, stream>>>(ybuf, wpb, out, M, C, C);
}

// Round 4
// 448.406 us; speedup vs baseline: 1.4755x; 1.0528x over previous
//
#include <hip/hip_runtime.h>
#include <hip/hip_bf16.h>
#include <cstdint>

#define N_HEAD 16
#define HEAD_DIM 128

typedef __bf16 bf16;
typedef __bf16 bf16x8 __attribute__((ext_vector_type(8)));
typedef __bf16 bf16x4 __attribute__((ext_vector_type(4)));
typedef float f32x4 __attribute__((ext_vector_type(4)));

// async global->LDS 16B (per-lane lds addr must be base + lane*16)
__device__ __forceinline__ void gload_lds16(const void* g, void* l) {
  auto gp = reinterpret_cast<const __attribute__((address_space(1))) char*>(
      reinterpret_cast<uintptr_t>(g));
  auto lp = reinterpret_cast<__attribute__((address_space(3))) char*>(
      reinterpret_cast<uintptr_t>(l));
  __builtin_amdgcn_global_load_lds(gp, lp, 16, 0, 0);
}

// ------- fp32 -> bf16 convert, all 5 tensors in one launch (z selects) ------
__global__ __launch_bounds__(256) void cvt_all(
    const float* __restrict__ x, const float* __restrict__ Wq,
    const float* __restrict__ Wk, const float* __restrict__ Wv,
    const float* __restrict__ Wp, bf16* __restrict__ xb,
    bf16* __restrict__ wqkv, bf16* __restrict__ wpb, int nx4, int nw4) {
  const int z = blockIdx.z;
  const float* in;
  bf16* out;
  int n4;
  if (z == 0)      { in = x;  out = xb;  n4 = nx4; }
  else if (z == 1) { in = Wq; out = wqkv;                     n4 = nw4; }
  else if (z == 2) { in = Wk; out = wqkv + (size_t)nw4 * 4;   n4 = nw4; }
  else if (z == 3) { in = Wv; out = wqkv + (size_t)nw4 * 8;   n4 = nw4; }
  else             { in = Wp; out = wpb;  n4 = nw4; }
  const int i = blockIdx.x * 256 + threadIdx.x;
  if (i >= n4) return;
  const float4 f = reinterpret_cast<const float4*>(in)[i];
  bf16x4 o;
  o.x = (bf16)f.x; o.y = (bf16)f.y; o.z = (bf16)f.z; o.w = (bf16)f.w;
  reinterpret_cast<bf16x4*>(out)[i] = o;
}

// ---------------- GEMM: C[M,N] = A[M,K] * B[N,K]^T (both row-major, bf16) ----
// 128x128 tile, BK=32, 4 waves (2x2 of 64x64), 16x16x32 bf16 MFMA.
template <typename OutT>
__global__ __launch_bounds__(256) void gemm_bt(
    const bf16* __restrict__ A, const bf16* __restrict__ Bt,
    OutT* __restrict__ C, int M, int N, int K) {
  __shared__ __align__(16) bf16 As[128 * 32];
  __shared__ __align__(16) bf16 Bs[128 * 32];
  const int tid = threadIdx.x;
  const int lane = tid & 63;
  const int wave = tid >> 6;
  const int wm = (wave >> 1) * 64;
  const int wn = (wave & 1) * 64;
  const int lr = lane & 15;
  const int lk = (lane >> 4) * 8;

  const bf16* Ab = A + (size_t)blockIdx.y * 128 * K;
  const bf16* Bb = Bt + (size_t)blockIdx.x * 128 * K;

  const int r0 = tid >> 2;        // 0..63, +64 on second pass
  const int c0 = (tid & 3) * 8;   // k-offset in elements

  f32x4 acc[4][4] = {};

  for (int k0 = 0; k0 < K; k0 += 32) {
    __syncthreads();
    gload_lds16(Ab + (size_t)r0 * K + k0 + c0, As + (size_t)tid * 8);
    gload_lds16(Ab + (size_t)(r0 + 64) * K + k0 + c0, As + (size_t)(256 + tid) * 8);
    gload_lds16(Bb + (size_t)r0 * K + k0 + c0, Bs + (size_t)tid * 8);
    gload_lds16(Bb + (size_t)(r0 + 64) * K + k0 + c0, Bs + (size_t)(256 + tid) * 8);
    __syncthreads();

    bf16x8 a[4], b[4];
#pragma unroll
    for (int i = 0; i < 4; ++i)
      a[i] = *reinterpret_cast<const bf16x8*>(As + (wm + i * 16 + lr) * 32 + lk);
#pragma unroll
    for (int j = 0; j < 4; ++j)
      b[j] = *reinterpret_cast<const bf16x8*>(Bs + (wn + j * 16 + lr) * 32 + lk);
#pragma unroll
    for (int i = 0; i < 4; ++i)
#pragma unroll
      for (int j = 0; j < 4; ++j)
        acc[i][j] = __builtin_amdgcn_mfma_f32_16x16x32_bf16(a[i], b[j], acc[i][j], 0, 0, 0);
  }

  const int orow = blockIdx.y * 128 + wm + (lane >> 4) * 4;
  const int ocol = blockIdx.x * 128 + wn + lr;
#pragma unroll
  for (int i = 0; i < 4; ++i)
#pragma unroll
    for (int j = 0; j < 4; ++j)
#pragma unroll
      for (int r = 0; r < 4; ++r)
        C[(size_t)(orow + i * 16 + r) * N + (ocol + j * 16)] = (OutT)acc[i][j][r];
}

// ---------------- rope + rms-norm, in-place on q,k inside qkv buffer --------
// grid: (B*T, H/4, 2[q|k]); one wave per head; lane i handles pair (i, i+64)
// q gets 1.2 * 1/sqrt(128) * log2(e) folded in (attn softmax runs in exp2 domain)
__global__ __launch_bounds__(256) void rope_rms(
    bf16* __restrict__ qkv, const float* __restrict__ cs,
    const float* __restrict__ sn, int T) {
  const int C = N_HEAD * HEAD_DIM;
  const int S = 3 * C;
  const int bt = blockIdx.x;
  const int t = bt % T;
  const int wave = threadIdx.x >> 6;
  const int lane = threadIdx.x & 63;
  const int h = blockIdx.y * 4 + wave;
  bf16* p = qkv + (size_t)bt * S + (blockIdx.z ? C : 0) + h * HEAD_DIM;
  // q: 1.2 * 0.08838834764831845 * 1.4426950408889634
  const float oscale = blockIdx.z ? 1.2f : 0.15302091809294977f;
  const float c = cs[t * 64 + lane];
  const float s = sn[t * 64 + lane];
  const float x1 = (float)p[lane];
  const float x2 = (float)p[lane + 64];
  const float r1 = x1 * c + x2 * s;
  const float r2 = x2 * c - x1 * s;
  float ss = r1 * r1 + r2 * r2;
#pragma unroll
  for (int m = 1; m < 64; m <<= 1) ss += __shfl_xor(ss, m);
  const float sc = oscale * rsqrtf(ss * (1.0f / 128.0f) + 1e-6f);
  p[lane] = (bf16)(r1 * sc);
  p[lane + 64] = (bf16)(r2 * sc);
}

// ---------------- gate + transpose: vT[b][h][d][t] = v[b][t][h][d] + gate*ve --
// v lives inside qkv at column offset 2C (row stride 3C).
// grid: (T/64, C/64, B), block 256. 64x64 tiles via padded LDS.
__global__ __launch_bounds__(256) void gate_transpose(
    const bf16* __restrict__ qkv, const float* __restrict__ x,
    const float* __restrict__ ve, const float* __restrict__ Wg,
    bf16* __restrict__ vT, int T) {
  const int C = N_HEAD * HEAD_DIM;
  const int S = 3 * C;
  const int t0 = blockIdx.x * 64;
  const int c0 = blockIdx.y * 64;
  const int b = blockIdx.z;
  const int h = c0 >> 7;

  __shared__ float gs[64];
  __shared__ __align__(16) bf16 tile[64][72];

  if (threadIdx.x < 64) {
    const float* xr = x + (size_t)(b * T + t0 + threadIdx.x) * C;
    float a = 0.f;
#pragma unroll
    for (int j = 0; j < 12; ++j) a += xr[j] * Wg[h * 12 + j];
    gs[threadIdx.x] = 3.f / (1.f + __expf(-a));
  }
  __syncthreads();

  {
    const int r = threadIdx.x >> 2;
    const int cc = (threadIdx.x & 3) * 16;
    const size_t vrow = (size_t)(b * T + t0 + r) * S + 2 * C + c0 + cc;
    const size_t erow = (size_t)(b * T + t0 + r) * C + c0 + cc;
    bf16x8 a0 = *reinterpret_cast<const bf16x8*>(qkv + vrow);
    bf16x8 a1 = *reinterpret_cast<const bf16x8*>(qkv + vrow + 8);
    const float g = gs[r];
    bf16x8 o0, o1;
#pragma unroll
    for (int i = 0; i < 8; ++i) o0[i] = (bf16)((float)a0[i] + g * ve[erow + i]);
#pragma unroll
    for (int i = 0; i < 8; ++i) o1[i] = (bf16)((float)a1[i] + g * ve[erow + 8 + i]);
    *reinterpret_cast<bf16x8*>(&tile[r][cc]) = o0;
    *reinterpret_cast<bf16x8*>(&tile[r][cc + 8]) = o1;
  }
  __syncthreads();
  {
    const int dr = threadIdx.x >> 2;        // col of tile = d offset
    const int tc = (threadIdx.x & 3) * 16;  // row of tile = t offset
    bf16x8 o0, o1;
#pragma unroll
    for (int i = 0; i < 8; ++i) o0[i] = tile[tc + i][dr];
#pragma unroll
    for (int i = 0; i < 8; ++i) o1[i] = tile[tc + 8 + i][dr];
    const size_t orow =
        ((size_t)((b * N_HEAD + h) * HEAD_DIM) + (c0 & 127) + dr) * T + t0 + tc;
    *reinterpret_cast<bf16x8*>(vT + orow) = o0;
    *reinterpret_cast<bf16x8*>(vT + orow + 8) = o1;
  }
}

// ---------------- flash attention, sliding window, LDS-staged --------------
// grid: (T/128, H, B); 4 waves; each wave owns TWO 16-q tiles (qb+w*16 and
// qb+64+w*16) sharing each staged 64-key chunk -> half the staging per q-row,
// 2x MFMA per barrier pair, inter-tile ILP. S^T = K*Q^T (per-lane scalar
// softmax, q = lane&15); O^T accumulated; V^T from pre-transposed global.
__global__ __launch_bounds__(256, 2) void attn(
    const bf16* __restrict__ qkv, const bf16* __restrict__ vT,
    bf16* __restrict__ y, const int* __restrict__ wptr, int T) {
  const int C = N_HEAD * HEAD_DIM;
  const int S = 3 * C;
  const int qb = blockIdx.x * 128;
  const int h = blockIdx.y;
  const int b = blockIdx.z;
  const int tid = threadIdx.x;
  const int wave = tid >> 6;
  const int lane = tid & 63;
  const int lm = lane & 15;
  const int quad = lane >> 4;

  const int w = wptr[0];
  const int W = (w > 0 && w < T) ? w : (1 << 30);

  __shared__ __align__(16) bf16 Ks[4][64][32];   // [d-chunk][key][32]  16 KB
  __shared__ __align__(16) bf16 Vs[2][128][32];  // [key-chunk][d][32]  16 KB
  __shared__ __align__(16) bf16 Pb[4][16][72];   // per-wave P          9 KB

  const bf16* kb = qkv + (size_t)b * T * S + C + (size_t)h * HEAD_DIM;
  const bf16* vb = vT + (size_t)((b * N_HEAD + h) * HEAD_DIM) * T;  // [128][T]

  const int qt[2] = {qb + wave * 16, qb + 64 + wave * 16};
  bf16x8 qf[2][4];
#pragma unroll
  for (int t = 0; t < 2; ++t) {
    const bf16* qrow = qkv + (size_t)(b * T + qt[t] + lm) * S + h * HEAD_DIM;
#pragma unroll
    for (int c = 0; c < 4; ++c)
      qf[t][c] = *reinterpret_cast<const bf16x8*>(qrow + c * 32 + quad * 8);
  }

  float mrun[2] = {-1e30f, -1e30f}, lrun[2] = {0.f, 0.f};
  f32x4 oacc[2][8] = {};

  int kstart = qb - W;
  if (kstart < 0) kstart = 0;
  kstart &= ~63;

  const int sr = tid >> 2;       // staging row 0..63
  const int sc = (tid & 3) * 8;  // staging col offset (elements)

  for (int kc = kstart; kc <= qb + 127; kc += 64) {
    __syncthreads();
    // stage K tile: 4 sub-tiles [64 keys][32 d]
#pragma unroll
    for (int c = 0; c < 4; ++c)
      gload_lds16(kb + (size_t)(kc + sr) * S + c * 32 + sc, &Ks[c][0][0] + tid * 8);
    // stage V^T tile: 2 sub-tiles [128 d][32 keys]
#pragma unroll
    for (int c2 = 0; c2 < 2; ++c2)
#pragma unroll
      for (int i = 0; i < 2; ++i)
        gload_lds16(vb + (size_t)(i * 64 + sr) * T + kc + c2 * 32 + sc,
                    &Vs[c2][i * 64][0] + tid * 8);
    __syncthreads();

#pragma unroll
    for (int t = 0; t < 2; ++t) {
      const int q0 = qt[t];
      // chunk entirely below this tile's window, or entirely above its rows
      if (kc > q0 + 15 || kc + 63 < q0 - W) continue;
      const int qr = q0 + lm;  // this lane's q row (softmax owner)

      // S^T[key][q] for 64 keys x 16 q
      f32x4 st[4] = {};
#pragma unroll
      for (int g = 0; g < 4; ++g)
#pragma unroll
        for (int c = 0; c < 4; ++c) {
          const bf16x8 kf =
              *reinterpret_cast<const bf16x8*>(&Ks[c][g * 16 + lm][quad * 8]);
          st[g] = __builtin_amdgcn_mfma_f32_16x16x32_bf16(kf, qf[t][c], st[g], 0, 0, 0);
        }
      // mask + local max (lane owns keys g*16+quad*4+r, single q row qr)
      float mx = -1e30f;
#pragma unroll
      for (int g = 0; g < 4; ++g)
#pragma unroll
        for (int r = 0; r < 4; ++r) {
          const int key = kc + g * 16 + quad * 4 + r;
          const bool valid = (key <= qr) && (qr - key <= W);
          st[g][r] = valid ? st[g][r] : -1e30f;
          mx = fmaxf(mx, st[g][r]);
        }
      mx = fmaxf(mx, __shfl_xor(mx, 16));
      mx = fmaxf(mx, __shfl_xor(mx, 32));
      const float mnew = fmaxf(mrun[t], mx);
      const float alpha = __builtin_amdgcn_exp2f(mrun[t] - mnew);
      mrun[t] = mnew;
      float rs = 0.f;
#pragma unroll
      for (int g = 0; g < 4; ++g) {
        bf16x4 pk;
#pragma unroll
        for (int r = 0; r < 4; ++r) {
          const float p = __builtin_amdgcn_exp2f(st[g][r] - mnew);
          rs += p;
          pk[r] = (bf16)p;
        }
        *reinterpret_cast<bf16x4*>(&Pb[wave][lm][g * 16 + quad * 4]) = pk;
      }
      rs += __shfl_xor(rs, 16);
      rs += __shfl_xor(rs, 32);
      lrun[t] = lrun[t] * alpha + rs;
#pragma unroll
      for (int dc = 0; dc < 8; ++dc)
#pragma unroll
        for (int r = 0; r < 4; ++r) oacc[t][dc][r] *= alpha;
      // O^T += V^T * P^T : A = V^T rows (d) from LDS, Bt = P rows (q) from LDS
#pragma unroll
      for (int c2 = 0; c2 < 2; ++c2) {
        const bf16x8 pf =
            *reinterpret_cast<const bf16x8*>(&Pb[wave][lm][c2 * 32 + quad * 8]);
#pragma unroll
        for (int dc = 0; dc < 8; ++dc) {
          const bf16x8 vf =
              *reinterpret_cast<const bf16x8*>(&Vs[c2][dc * 16 + lm][quad * 8]);
          oacc[t][dc] = __builtin_amdgcn_mfma_f32_16x16x32_bf16(vf, pf, oacc[t][dc], 0, 0, 0);
        }
      }
    }
  }

#pragma unroll
  for (int t = 0; t < 2; ++t) {
    const float inv = 1.f / lrun[t];
    bf16* yr = y + (size_t)(b * T + qt[t] + lm) * C + h * HEAD_DIM;
#pragma unroll
    for (int dc = 0; dc < 8; ++dc) {
      bf16x4 o;
#pragma unroll
      for (int r = 0; r < 4; ++r) o[r] = (bf16)(oacc[t][dc][r] * inv);
      *reinterpret_cast<bf16x4*>(yr + dc * 16 + quad * 4) = o;
    }
  }
}

extern "C" void kernel_launch(void* const* d_in, const int* in_sizes, int n_in,
                              void* d_out, int out_size, void* d_ws, size_t ws_size,
                              hipStream_t stream) {
  const float* x  = (const float*)d_in[0];
  const float* ve = (const float*)d_in[1];
  const float* Wq = (const float*)d_in[2];
  const float* Wk = (const float*)d_in[3];
  const float* Wv = (const float*)d_in[4];
  const float* Wp = (const float*)d_in[5];
  const float* Wg = (const float*)d_in[6];
  const float* cs = (const float*)d_in[7];
  const float* sn = (const float*)d_in[8];
  const int*   wl = (const int*)d_in[9];
  float* out = (float*)d_out;

  const int C = N_HEAD * HEAD_DIM;       // 2048
  const int T = in_sizes[7] / (HEAD_DIM / 2);
  const int B = in_sizes[0] / (T * C);
  const int M = B * T;

  bf16* xb   = (bf16*)d_ws;                    // [M][C]
  bf16* wqkv = xb   + (size_t)M * C;           // [3C][C] (Wq|Wk|Wv rows)
  bf16* wpb  = wqkv + (size_t)3 * C * C;       // [C][C]
  bf16* qkv  = wpb  + (size_t)C * C;           // [M][3C]
  bf16* ybuf = qkv  + (size_t)3 * M * C;       // [M][C]
  bf16* vTb  = xb;  // xb dead after QKV GEMM; reuse for V^T [B][H][128][T]

  const int nx4 = M * C / 4, nw4 = C * C / 4;
  cvt_all<<<dim3((nx4 + 255) / 256, 1, 5), 256, 0, stream>>>(
      x, Wq, Wk, Wv, Wp, xb, wqkv, wpb, nx4, nw4);

  // fused QKV: [M,3C] = xb[M,K] * wqkv[3C,K]^T
  gemm_bt<bf16><<<dim3(3 * C / 128, M / 128), 256, 0, stream>>>(xb, wqkv, qkv, M, 3 * C, C);

  rope_rms<<<dim3(M, N_HEAD / 4, 2), 256, 0, stream>>>(qkv, cs, sn, T);
  gate_transpose<<<dim3(T / 64, C / 64, B), 256, 0, stream>>>(qkv, x, ve, Wg, vTb, T);
  attn<<<dim3(T / 128, N_HEAD, B), 256, 0, stream>>>(qkv, vTb, ybuf, wl, T);

  gemm_bt<float><<<dim3(C / 128, M / 128), 256, 0, stream>>>(ybuf, wpb, out, M, C, C);
}

// Round 6
// 426.071 us; speedup vs baseline: 1.5528x; 1.0524x over previous
//
#include <hip/hip_runtime.h>
#include <hip/hip_bf16.h>
#include <cstdint>

#define N_HEAD 16
#define HEAD_DIM 128

typedef __bf16 bf16;
typedef __bf16 bf16x8 __attribute__((ext_vector_type(8)));
typedef __bf16 bf16x4 __attribute__((ext_vector_type(4)));
typedef float f32x4 __attribute__((ext_vector_type(4)));

// async global->LDS 16B (per-lane lds addr must be base + lane*16)
__device__ __forceinline__ void gload_lds16(const void* g, void* l) {
  auto gp = reinterpret_cast<const __attribute__((address_space(1))) char*>(
      reinterpret_cast<uintptr_t>(g));
  auto lp = reinterpret_cast<__attribute__((address_space(3))) char*>(
      reinterpret_cast<uintptr_t>(l));
  __builtin_amdgcn_global_load_lds(gp, lp, 16, 0, 0);
}

// ------- fp32 -> bf16 convert, all 5 tensors in one launch (z selects) ------
__global__ __launch_bounds__(256) void cvt_all(
    const float* __restrict__ x, const float* __restrict__ Wq,
    const float* __restrict__ Wk, const float* __restrict__ Wv,
    const float* __restrict__ Wp, bf16* __restrict__ xb,
    bf16* __restrict__ wqkv, bf16* __restrict__ wpb, int nx4, int nw4) {
  const int z = blockIdx.z;
  const float* in;
  bf16* out;
  int n4;
  if (z == 0)      { in = x;  out = xb;  n4 = nx4; }
  else if (z == 1) { in = Wq; out = wqkv;                     n4 = nw4; }
  else if (z == 2) { in = Wk; out = wqkv + (size_t)nw4 * 4;   n4 = nw4; }
  else if (z == 3) { in = Wv; out = wqkv + (size_t)nw4 * 8;   n4 = nw4; }
  else             { in = Wp; out = wpb;  n4 = nw4; }
  const int i = blockIdx.x * 256 + threadIdx.x;
  if (i >= n4) return;
  const float4 f = reinterpret_cast<const float4*>(in)[i];
  bf16x4 o;
  o.x = (bf16)f.x; o.y = (bf16)f.y; o.z = (bf16)f.z; o.w = (bf16)f.w;
  reinterpret_cast<bf16x4*>(out)[i] = o;
}

// ---------------- GEMM: C[M,N] = A[M,K] * B[N,K]^T (both row-major, bf16) ----
// 128x128 tile, BK=64 (two 32-k sub-tiles, m97 sub-tile layout), 4 waves
// (2x2 of 64x64), 16x16x32 bf16 MFMA. BK=64 halves barrier count vs BK=32;
// LDS 32 KB keeps occupancy (VGPR-bound anyway).
template <typename OutT>
__global__ __launch_bounds__(256) void gemm_bt(
    const bf16* __restrict__ A, const bf16* __restrict__ Bt,
    OutT* __restrict__ C, int M, int N, int K) {
  __shared__ __align__(16) bf16 As[2][128 * 32];
  __shared__ __align__(16) bf16 Bs[2][128 * 32];
  const int tid = threadIdx.x;
  const int lane = tid & 63;
  const int wave = tid >> 6;
  const int wm = (wave >> 1) * 64;
  const int wn = (wave & 1) * 64;
  const int lr = lane & 15;
  const int lk = (lane >> 4) * 8;

  const bf16* Ab = A + (size_t)blockIdx.y * 128 * K;
  const bf16* Bb = Bt + (size_t)blockIdx.x * 128 * K;

  const int r0 = tid >> 2;        // 0..63, +64 on second pass
  const int c0 = (tid & 3) * 8;   // k-offset in elements

  f32x4 acc[4][4] = {};

  for (int k0 = 0; k0 < K; k0 += 64) {
    __syncthreads();
#pragma unroll
    for (int s = 0; s < 2; ++s) {
      const int kk = k0 + s * 32 + c0;
      gload_lds16(Ab + (size_t)r0 * K + kk, As[s] + (size_t)tid * 8);
      gload_lds16(Ab + (size_t)(r0 + 64) * K + kk, As[s] + (size_t)(256 + tid) * 8);
      gload_lds16(Bb + (size_t)r0 * K + kk, Bs[s] + (size_t)tid * 8);
      gload_lds16(Bb + (size_t)(r0 + 64) * K + kk, Bs[s] + (size_t)(256 + tid) * 8);
    }
    __syncthreads();

#pragma unroll
    for (int s = 0; s < 2; ++s) {
      bf16x8 a[4], b[4];
#pragma unroll
      for (int i = 0; i < 4; ++i)
        a[i] = *reinterpret_cast<const bf16x8*>(As[s] + (wm + i * 16 + lr) * 32 + lk);
#pragma unroll
      for (int j = 0; j < 4; ++j)
        b[j] = *reinterpret_cast<const bf16x8*>(Bs[s] + (wn + j * 16 + lr) * 32 + lk);
#pragma unroll
      for (int i = 0; i < 4; ++i)
#pragma unroll
        for (int j = 0; j < 4; ++j)
          acc[i][j] = __builtin_amdgcn_mfma_f32_16x16x32_bf16(a[i], b[j], acc[i][j], 0, 0, 0);
    }
  }

  const int orow = blockIdx.y * 128 + wm + (lane >> 4) * 4;
  const int ocol = blockIdx.x * 128 + wn + lr;
#pragma unroll
  for (int i = 0; i < 4; ++i)
#pragma unroll
    for (int j = 0; j < 4; ++j)
#pragma unroll
      for (int r = 0; r < 4; ++r)
        C[(size_t)(orow + i * 16 + r) * N + (ocol + j * 16)] = (OutT)acc[i][j][r];
}

// ---------------- rope + rms-norm, in-place on q,k inside qkv buffer --------
__global__ __launch_bounds__(256) void rope_rms(
    bf16* __restrict__ qkv, const float* __restrict__ cs,
    const float* __restrict__ sn, int T) {
  const int C = N_HEAD * HEAD_DIM;
  const int S = 3 * C;
  const int bt = blockIdx.x;
  const int t = bt % T;
  const int wave = threadIdx.x >> 6;
  const int lane = threadIdx.x & 63;
  const int h = blockIdx.y * 4 + wave;
  bf16* p = qkv + (size_t)bt * S + (blockIdx.z ? C : 0) + h * HEAD_DIM;
  // q: 1.2 * 0.08838834764831845 * 1.4426950408889634 (exp2-domain softmax)
  const float oscale = blockIdx.z ? 1.2f : 0.15302091809294977f;
  const float c = cs[t * 64 + lane];
  const float s = sn[t * 64 + lane];
  const float x1 = (float)p[lane];
  const float x2 = (float)p[lane + 64];
  const float r1 = x1 * c + x2 * s;
  const float r2 = x2 * c - x1 * s;
  float ss = r1 * r1 + r2 * r2;
#pragma unroll
  for (int m = 1; m < 64; m <<= 1) ss += __shfl_xor(ss, m);
  const float sc = oscale * rsqrtf(ss * (1.0f / 128.0f) + 1e-6f);
  p[lane] = (bf16)(r1 * sc);
  p[lane + 64] = (bf16)(r2 * sc);
}

// ---------------- gate + transpose: vT[b][h][d][t] = v[b][t][h][d] + gate*ve --
__global__ __launch_bounds__(256) void gate_transpose(
    const bf16* __restrict__ qkv, const float* __restrict__ x,
    const float* __restrict__ ve, const float* __restrict__ Wg,
    bf16* __restrict__ vT, int T) {
  const int C = N_HEAD * HEAD_DIM;
  const int S = 3 * C;
  const int t0 = blockIdx.x * 64;
  const int c0 = blockIdx.y * 64;
  const int b = blockIdx.z;
  const int h = c0 >> 7;

  __shared__ float gs[64];
  __shared__ __align__(16) bf16 tile[64][72];

  if (threadIdx.x < 64) {
    const float* xr = x + (size_t)(b * T + t0 + threadIdx.x) * C;
    float a = 0.f;
#pragma unroll
    for (int j = 0; j < 12; ++j) a += xr[j] * Wg[h * 12 + j];
    gs[threadIdx.x] = 3.f / (1.f + __expf(-a));
  }
  __syncthreads();

  {
    const int r = threadIdx.x >> 2;
    const int cc = (threadIdx.x & 3) * 16;
    const size_t vrow = (size_t)(b * T + t0 + r) * S + 2 * C + c0 + cc;
    const size_t erow = (size_t)(b * T + t0 + r) * C + c0 + cc;
    bf16x8 a0 = *reinterpret_cast<const bf16x8*>(qkv + vrow);
    bf16x8 a1 = *reinterpret_cast<const bf16x8*>(qkv + vrow + 8);
    const float g = gs[r];
    bf16x8 o0, o1;
#pragma unroll
    for (int i = 0; i < 8; ++i) o0[i] = (bf16)((float)a0[i] + g * ve[erow + i]);
#pragma unroll
    for (int i = 0; i < 8; ++i) o1[i] = (bf16)((float)a1[i] + g * ve[erow + 8 + i]);
    *reinterpret_cast<bf16x8*>(&tile[r][cc]) = o0;
    *reinterpret_cast<bf16x8*>(&tile[r][cc + 8]) = o1;
  }
  __syncthreads();
  {
    const int dr = threadIdx.x >> 2;        // col of tile = d offset
    const int tc = (threadIdx.x & 3) * 16;  // row of tile = t offset
    bf16x8 o0, o1;
#pragma unroll
    for (int i = 0; i < 8; ++i) o0[i] = tile[tc + i][dr];
#pragma unroll
    for (int i = 0; i < 8; ++i) o1[i] = tile[tc + 8 + i][dr];
    const size_t orow =
        ((size_t)((b * N_HEAD + h) * HEAD_DIM) + (c0 & 127) + dr) * T + t0 + tc;
    *reinterpret_cast<bf16x8*>(vT + orow) = o0;
    *reinterpret_cast<bf16x8*>(vT + orow + 8) = o1;
  }
}

// ---------------- flash attention, sliding window, LDS-staged --------------
// 1-D grid B*H*(T/128), XCD-swizzled so all q-blocks of one (b,h) share an
// XCD's L2. 4 waves; each wave owns TWO 16-q tiles sharing each staged
// 64-key chunk. Register-prefetch double buffer: chunk k+1 global->VGPR
// loads issue before chunk k's compute; LDS commit at next iteration top.
// S^T = K*Q^T (per-lane scalar softmax, q = lane&15); O^T accumulated.
__global__ __launch_bounds__(256, 2) void attn(
    const bf16* __restrict__ qkv, const bf16* __restrict__ vT,
    bf16* __restrict__ y, const int* __restrict__ wptr, int T, int B) {
  const int C = N_HEAD * HEAD_DIM;
  const int S = 3 * C;
  const int nq = T >> 7;                       // q-blocks per (b,h)
  const int ppx = (B * N_HEAD) >> 3;           // (b,h) pairs per XCD
  const int bid = blockIdx.x;
  const int xcd = bid & 7;
  const int sl = bid >> 3;
  const int pair = xcd * ppx + sl / nq;
  const int qi = sl % nq;
  const int b = pair / N_HEAD;
  const int h = pair % N_HEAD;
  const int qb = qi * 128;

  const int tid = threadIdx.x;
  const int wave = tid >> 6;
  const int lane = tid & 63;
  const int lm = lane & 15;
  const int quad = lane >> 4;

  const int w = wptr[0];
  const int W = (w > 0 && w < T) ? w : (1 << 30);

  __shared__ __align__(16) bf16 Ks[4][64][32];   // [d-chunk][key][32]  16 KB
  __shared__ __align__(16) bf16 Vs[2][128][32];  // [key-chunk][d][32]  16 KB
  __shared__ __align__(16) bf16 Pb[4][16][72];   // per-wave P[q][64key]  9 KB
                                                 // row=72: 64 keys + 8 pad!

  const bf16* kb = qkv + (size_t)b * T * S + C + (size_t)h * HEAD_DIM;
  const bf16* vb = vT + (size_t)((b * N_HEAD + h) * HEAD_DIM) * T;  // [128][T]

  const int qt[2] = {qb + wave * 16, qb + 64 + wave * 16};
  bf16x8 qf[2][4];
#pragma unroll
  for (int t = 0; t < 2; ++t) {
    const bf16* qrow = qkv + (size_t)(b * T + qt[t] + lm) * S + h * HEAD_DIM;
#pragma unroll
    for (int c = 0; c < 4; ++c)
      qf[t][c] = *reinterpret_cast<const bf16x8*>(qrow + c * 32 + quad * 8);
  }

  float mrun[2] = {-1e30f, -1e30f}, lrun[2] = {0.f, 0.f};
  f32x4 oacc[2][8] = {};

  int kstart = qb - W;
  if (kstart < 0) kstart = 0;
  kstart &= ~63;
  const int kend = qb + 64;  // last chunk start

  const int sr = tid >> 2;       // staging row 0..63
  const int sc = (tid & 3) * 8;  // staging col offset (elements)

  // prefetch registers: K chunk (4x16B) + V^T chunk (4x16B)
  bf16x8 kpre[4], vpre[4];
  {
    const bf16* kr = kb + (size_t)(kstart + sr) * S + sc;
#pragma unroll
    for (int c = 0; c < 4; ++c)
      kpre[c] = *reinterpret_cast<const bf16x8*>(kr + c * 32);
#pragma unroll
    for (int c2 = 0; c2 < 2; ++c2)
#pragma unroll
      for (int i = 0; i < 2; ++i)
        vpre[c2 * 2 + i] = *reinterpret_cast<const bf16x8*>(
            vb + (size_t)(i * 64 + sr) * T + kstart + c2 * 32 + sc);
  }

  for (int kc = kstart; kc <= kend; kc += 64) {
    __syncthreads();
    // commit prefetched chunk to LDS (vmcnt wait lands here, after the
    // previous iteration's compute)
#pragma unroll
    for (int c = 0; c < 4; ++c)
      *reinterpret_cast<bf16x8*>(&Ks[c][sr][sc]) = kpre[c];
#pragma unroll
    for (int c2 = 0; c2 < 2; ++c2)
#pragma unroll
      for (int i = 0; i < 2; ++i)
        *reinterpret_cast<bf16x8*>(&Vs[c2][i * 64 + sr][sc]) = vpre[c2 * 2 + i];
    __syncthreads();

    // issue next chunk's global loads before compute
    if (kc + 64 <= kend) {
      const int kc2 = kc + 64;
      const bf16* kr = kb + (size_t)(kc2 + sr) * S + sc;
#pragma unroll
      for (int c = 0; c < 4; ++c)
        kpre[c] = *reinterpret_cast<const bf16x8*>(kr + c * 32);
#pragma unroll
      for (int c2 = 0; c2 < 2; ++c2)
#pragma unroll
        for (int i = 0; i < 2; ++i)
          vpre[c2 * 2 + i] = *reinterpret_cast<const bf16x8*>(
              vb + (size_t)(i * 64 + sr) * T + kc2 + c2 * 32 + sc);
    }

#pragma unroll
    for (int t = 0; t < 2; ++t) {
      const int q0 = qt[t];
      // chunk entirely above this tile's rows, or below its window
      if (kc > q0 + 15 || kc + 63 < q0 - W) continue;
      const int qr = q0 + lm;  // this lane's q row (softmax owner)

      // S^T[key][q] for 64 keys x 16 q
      f32x4 st[4] = {};
#pragma unroll
      for (int g = 0; g < 4; ++g)
#pragma unroll
        for (int c = 0; c < 4; ++c) {
          const bf16x8 kf =
              *reinterpret_cast<const bf16x8*>(&Ks[c][g * 16 + lm][quad * 8]);
          st[g] = __builtin_amdgcn_mfma_f32_16x16x32_bf16(kf, qf[t][c], st[g], 0, 0, 0);
        }
      // mask + local max (lane owns keys g*16+quad*4+r, single q row qr)
      float mx = -1e30f;
#pragma unroll
      for (int g = 0; g < 4; ++g)
#pragma unroll
        for (int r = 0; r < 4; ++r) {
          const int key = kc + g * 16 + quad * 4 + r;
          const bool valid = (key <= qr) && (qr - key <= W);
          st[g][r] = valid ? st[g][r] : -1e30f;
          mx = fmaxf(mx, st[g][r]);
        }
      mx = fmaxf(mx, __shfl_xor(mx, 16));
      mx = fmaxf(mx, __shfl_xor(mx, 32));
      const float mnew = fmaxf(mrun[t], mx);
      const float alpha = __builtin_amdgcn_exp2f(mrun[t] - mnew);
      mrun[t] = mnew;
      float rs = 0.f;
#pragma unroll
      for (int g = 0; g < 4; ++g) {
        bf16x4 pk;
#pragma unroll
        for (int r = 0; r < 4; ++r) {
          const float p = __builtin_amdgcn_exp2f(st[g][r] - mnew);
          rs += p;
          pk[r] = (bf16)p;
        }
        *reinterpret_cast<bf16x4*>(&Pb[wave][lm][g * 16 + quad * 4]) = pk;
      }
      rs += __shfl_xor(rs, 16);
      rs += __shfl_xor(rs, 32);
      lrun[t] = lrun[t] * alpha + rs;
#pragma unroll
      for (int dc = 0; dc < 8; ++dc)
#pragma unroll
        for (int r = 0; r < 4; ++r) oacc[t][dc][r] *= alpha;
      // O^T += V^T * P^T : A = V^T rows (d) from LDS, Bt = P rows (q) from LDS
#pragma unroll
      for (int c2 = 0; c2 < 2; ++c2) {
        const bf16x8 pf =
            *reinterpret_cast<const bf16x8*>(&Pb[wave][lm][c2 * 32 + quad * 8]);
#pragma unroll
        for (int dc = 0; dc < 8; ++dc) {
          const bf16x8 vf =
              *reinterpret_cast<const bf16x8*>(&Vs[c2][dc * 16 + lm][quad * 8]);
          oacc[t][dc] = __builtin_amdgcn_mfma_f32_16x16x32_bf16(vf, pf, oacc[t][dc], 0, 0, 0);
        }
      }
    }
  }

#pragma unroll
  for (int t = 0; t < 2; ++t) {
    const float inv = 1.f / lrun[t];
    bf16* yr = y + (size_t)(b * T + qt[t] + lm) * C + h * HEAD_DIM;
#pragma unroll
    for (int dc = 0; dc < 8; ++dc) {
      bf16x4 o;
#pragma unroll
      for (int r = 0; r < 4; ++r) o[r] = (bf16)(oacc[t][dc][r] * inv);
      *reinterpret_cast<bf16x4*>(yr + dc * 16 + quad * 4) = o;
    }
  }
}

extern "C" void kernel_launch(void* const* d_in, const int* in_sizes, int n_in,
                              void* d_out, int out_size, void* d_ws, size_t ws_size,
                              hipStream_t stream) {
  const float* x  = (const float*)d_in[0];
  const float* ve = (const float*)d_in[1];
  const float* Wq = (const float*)d_in[2];
  const float* Wk = (const float*)d_in[3];
  const float* Wv = (const float*)d_in[4];
  const float* Wp = (const float*)d_in[5];
  const float* Wg = (const float*)d_in[6];
  const float* cs = (const float*)d_in[7];
  const float* sn = (const float*)d_in[8];
  const int*   wl = (const int*)d_in[9];
  float* out = (float*)d_out;

  const int C = N_HEAD * HEAD_DIM;       // 2048
  const int T = in_sizes[7] / (HEAD_DIM / 2);
  const int B = in_sizes[0] / (T * C);
  const int M = B * T;

  bf16* xb   = (bf16*)d_ws;                    // [M][C]
  bf16* wqkv = xb   + (size_t)M * C;           // [3C][C] (Wq|Wk|Wv rows)
  bf16* wpb  = wqkv + (size_t)3 * C * C;       // [C][C]
  bf16* qkv  = wpb  + (size_t)C * C;           // [M][3C]
  bf16* ybuf = qkv  + (size_t)3 * M * C;       // [M][C]
  bf16* vTb  = xb;  // xb dead after QKV GEMM; reuse for V^T [B][H][128][T]

  const int nx4 = M * C / 4, nw4 = C * C / 4;
  cvt_all<<<dim3((nx4 + 255) / 256, 1, 5), 256, 0, stream>>>(
      x, Wq, Wk, Wv, Wp, xb, wqkv, wpb, nx4, nw4);

  // fused QKV: [M,3C] = xb[M,K] * wqkv[3C,K]^T
  gemm_bt<bf16><<<dim3(3 * C / 128, M / 128), 256, 0, stream>>>(xb, wqkv, qkv, M, 3 * C, C);

  rope_rms<<<dim3(M, N_HEAD / 4, 2), 256, 0, stream>>>(qkv, cs, sn, T);
  gate_transpose<<<dim3(T / 64, C / 64, B), 256, 0, stream>>>(qkv, x, ve, Wg, vTb, T);
  attn<<<dim3(B * N_HEAD * (T / 128)), 256, 0, stream>>>(qkv, vTb, ybuf, wl, T, B);

  gemm_bt<float><<<dim3(C / 128, M / 128), 256, 0, stream>>>(ybuf, wpb, out, M, C, C);
}